// Round 3
// baseline (295.447 us; speedup 1.0000x reference)
//
#include <hip/hip_runtime.h>

// PointPillarScatter on MI355X (gfx950)
// R7: thread = one x-quad, loops all 8 channel groups.
//  - map read ONCE per thread (R6 showed map reloads were L1-hits / null)
//  - feat rows read sequentially 32B/cg -> L1/L2 line reuse across 4 cgs
//  - miss cells point at a 256B zero-row in ws -> UNCONDITIONAL feat loads
//    (no divergence, static vmcnt so loads(cg+1) overlap stores(cg))
//  - frA/frB ping-pong, fully unrolled (static reg indexing)
//  - NT stores (R5 proved plain stores -7us: keep L2 for map/feat)
#define GNX 512
#define GNY 512
#define GC  64

typedef float vfloat4 __attribute__((ext_vector_type(4)));
typedef int   vint4   __attribute__((ext_vector_type(4)));

// Step 0: fill cell->pillar map with -1; zero the dummy zero-row after it.
__global__ void pp_fill_map(vint4* __restrict__ map, int n4) {
    int i = blockIdx.x * blockDim.x + threadIdx.x;
    if (i < n4) {
        vint4 m1 = { -1, -1, -1, -1 };
        map[i] = m1;
    }
    if (i < 16) {                      // 16 x 16B = 256B zero row at map+n4
        vint4 z = { 0, 0, 0, 0 };
        map[n4 + i] = z;
    }
}

// Step 1: scatter pillar index p into dense (b, y, x) -> p map. coords int32.
__global__ void pp_scatter_idx(const vint4* __restrict__ coords,
                               int* __restrict__ map, int P) {
    int p = blockIdx.x * blockDim.x + threadIdx.x;
    if (p >= P) return;
    vint4 c = coords[p];                       // [b, z, y, x]
    map[c[0] * (GNY * GNX) + c[1] + c[2] * GNX + c[3]] = p;
}

#define LOADCG(fr, cg) do {                                            \
    int off_ = ((cg) << 3);                                            \
    _Pragma("unroll")                                                  \
    for (int j = 0; j < 4; ++j) {                                      \
        const vfloat4* fp_ = (const vfloat4*)(bj[j] + off_);           \
        fr[j][0] = fp_[0];                                             \
        fr[j][1] = fp_[1];                                             \
    }                                                                  \
} while (0)

#define STORECG(fr, cg) do {                                           \
    float* ob_ = obase + (((cg) << 3) << 18);                          \
    _Pragma("unroll")                                                  \
    for (int k = 0; k < 2; ++k)                                        \
    _Pragma("unroll")                                                  \
    for (int t = 0; t < 4; ++t) {                                      \
        vfloat4 v_ = { fr[0][k][t], fr[1][k][t], fr[2][k][t], fr[3][k][t] }; \
        __builtin_nontemporal_store(v_, (vfloat4*)(ob_ + (((k << 2) + t) << 18))); \
    }                                                                  \
} while (0)

// Step 2: gather. Thread = x-quad; loops cg = 0..7 with load/store ping-pong.
__global__ void __launch_bounds__(256) pp_gather_out(
        const float* __restrict__ feat, const int* __restrict__ map,
        const float* __restrict__ zrow, float* __restrict__ out, int nquad) {
    int q = blockIdx.x * blockDim.x + threadIdx.x;
    if (q >= nquad) return;

    int x4 = q & (GNX / 4 - 1);
    int y  = (q >> 7) & (GNY - 1);
    int b  = q >> 16;

    vint4 m = *(const vint4*)(map + (b << 18) + (y << 9) + (x4 << 2));

    // per-cell feature row base; empty cells -> shared 256B zero row
    const float* bj[4];
#pragma unroll
    for (int j = 0; j < 4; ++j) {
        int pj = m[j];
        bj[j] = (pj >= 0) ? (feat + (pj << 6)) : zrow;
    }

    float* obase = out + (((b << 6)) << 18) + (y << 9) + (x4 << 2);

    vfloat4 frA[4][2], frB[4][2];
    LOADCG(frA, 0);
#pragma unroll
    for (int c2 = 0; c2 < 4; ++c2) {
        LOADCG(frB, 2 * c2 + 1);       // issue odd-cg loads
        STORECG(frA, 2 * c2);          // store even cg (waits only its loads)
        if (c2 < 3) LOADCG(frA, 2 * c2 + 2);
        STORECG(frB, 2 * c2 + 1);
    }
}

extern "C" void kernel_launch(void* const* d_in, const int* in_sizes, int n_in,
                              void* d_out, int out_size, void* d_ws, size_t ws_size,
                              hipStream_t stream) {
    const float* feat   = (const float*)d_in[0];
    const int*   coords = (const int*)d_in[1];   // int32 (harness converts int64)
    int P = in_sizes[1] / 4;                     // 120000
    int B = out_size / (GC * GNY * GNX);         // 4
    int* map = (int*)d_ws;
    int mapN = B * GNY * GNX;                    // 1,048,576 ints (4 MiB)
    const float* zrow = (const float*)(map + mapN);  // 256B zero row

    int n4 = mapN / 4;
    pp_fill_map<<<(n4 + 255) / 256, 256, 0, stream>>>((vint4*)map, n4);
    pp_scatter_idx<<<(P + 255) / 256, 256, 0, stream>>>(
        (const vint4*)coords, map, P);

    int nquad = B * GNY * (GNX / 4);             // 262,144 x-quads
    pp_gather_out<<<(nquad + 255) / 256, 256, 0, stream>>>(
        feat, map, zrow, (float*)d_out, nquad);
}